// Round 9
// baseline (18.956 us; speedup 1.0000x reference)
//
#include <hip/hip_runtime.h>

// Problem constants (fixed by the reference)
#define BB   4096
#define NN   16
#define AA   8
#define DIN  128
#define H1C  64
#define DPC  64
#define DZC  64

#define GENV 16    // envs per block (grid = 256 = 1 block/CU)
#define WENV 2     // envs per wave, software-pipelined
#define NTHR 512   // 8 waves

// Collapsed reference (round-0 derivation; verified passing R1/R3..R8):
//   agg   = mean_n obs[b,n,:]                      [128]
//   h     = relu(agg @ W1 + b1)                    [64]
//   (p eliminated:)  u = Wfc @ (Wattn[:64]+Wattn[64:]);  v1 = W2 @ u;  v2 = W2 @ Wv[:64]
//   logit = h.v1 + b2.u ;  wgt = sigmoid(leaky_relu(logit))   -> entire w output
//   c     = h.v2 + b2.Wv[:64] + bv
//   dv[j] = (pi[b,j]-act[b,j]) . Wv[64:72]         [16]
//   Sv    = sum(pi.v) - wgt * sum((pi-act).v)
//   x[b,d,j] = c + (Sv + wgt*dv[j]) / 16           (independent of d)

__device__ __forceinline__ float lane_bcast(float v, int lane) {
    return __int_as_float(__builtin_amdgcn_readlane(__float_as_int(v), lane));
}

__global__ __launch_bounds__(NTHR, 2)
void critic_kernel(const float* __restrict__ obs,      // [B*N, 128]
                   const float* __restrict__ policies, // [B*N, 8]
                   const float* __restrict__ actions,  // [B*N, 8]
                   const float* __restrict__ W1,       // [128,64]
                   const float* __restrict__ b1,       // [64]
                   const float* __restrict__ W2,       // [64,64]
                   const float* __restrict__ b2,       // [64]
                   const float* __restrict__ Wfc,      // [64,64]
                   const float* __restrict__ Wattn,    // [128]
                   const float* __restrict__ Wv,       // [72]
                   const float* __restrict__ bv,       // [1]
                   float* __restrict__ out_x,          // [B*N*N]
                   float* __restrict__ out_w)          // [B*N*N]
{
    // W1 transposed tile, XOR-swizzled at float4 granularity (R8-passing):
    //   [c][4*d4..4*d4+3] lives at sW1T4[c*32 + (d4 ^ (c&7))]  -> conflict-free b128.
    __shared__ float4 sW1T4[H1C * 32];  // 32 KB
    __shared__ float sV1[H1C];
    __shared__ float sV2[H1C];
    __shared__ float sS[2];             // tb2u, tb2w
    __shared__ float sDv[GENV][16];     // 1 KB
    __shared__ float sWsum[DZC];        // wave-7 scratch
    __shared__ float sWv64[DPC];
    __shared__ float sU[DPC];           // ~34.3 KB total

    const int tid = threadIdx.x;
    const int l   = tid & 63;
    const int w   = tid >> 6;                    // wave id
    const int leA = 2 * w;                       // local envs of this wave
    const int leB = 2 * w + 1;
    const int eA  = blockIdx.x * GENV + leA;
    const int eB  = blockIdx.x * GENV + leB;

    // ---- stage W1 transposed+swizzled (R8 form): 4 coalesced scalar load
    //      quads -> conflict-free ds_write_b128; once per 16 envs. ----
    {
        const int c   = tid & 63;
        const int grp = tid >> 6;
        #pragma unroll
        for (int i = 0; i < 4; ++i) {
            const int d0 = 4 * (i * 8 + grp);     // 0,4,...,124
            const float w0  = W1[(d0 + 0) * H1C + c];
            const float w1_ = W1[(d0 + 1) * H1C + c];
            const float w2_ = W1[(d0 + 2) * H1C + c];
            const float w3_ = W1[(d0 + 3) * H1C + c];
            sW1T4[c * 32 + ((d0 >> 2) ^ (c & 7))] = make_float4(w0, w1_, w2_, w3_);
        }
    }

    // ---- env A obs loads (R1 float4 layout: lane l, iter t -> 1 KB/instr) ----
    const float4* o4A = reinterpret_cast<const float4*>(obs + (size_t)eA * NN * DIN);
    const float4* o4B = reinterpret_cast<const float4*>(obs + (size_t)eB * NN * DIN);
    float4 ovA[8];
    #pragma unroll
    for (int t = 0; t < 8; ++t) ovA[t] = o4A[t * 64 + l];

    // ---- pol/act loads, both envs (tiny; early issue) ----
    float pv0[WENV], pv1[WENV], av0[WENV], av1[WENV];
    {
        const float* PbA = policies + (size_t)eA * (NN * AA);
        const float* AbA = actions  + (size_t)eA * (NN * AA);
        const float* PbB = policies + (size_t)eB * (NN * AA);
        const float* AbB = actions  + (size_t)eB * (NN * AA);
        pv0[0] = PbA[l]; pv1[0] = PbA[64 + l]; av0[0] = AbA[l]; av1[0] = AbA[64 + l];
        pv0[1] = PbB[l]; pv1[1] = PbB[64 + l]; av0[1] = AbB[l]; av1[1] = AbB[64 + l];
    }

    // ---- small params ----
    const float b1v = b1[l];
    const float va  = Wv[64 + (l & 7)];
    const float bvv = bv[0];

    // ---- wave 7: env-independent u/v1/v2 (R8-passing form, same-wave LDS) ----
    if (w == 7) {
        const float b2v  = b2[l];
        const float wsum = Wattn[l] + Wattn[DZC + l];
        const float wvv  = Wv[l];
        sWsum[l] = wsum;
        sWv64[l] = wvv;

        float u = 0.0f;
        {
            const float4* WfcR = reinterpret_cast<const float4*>(Wfc) + (size_t)l * (DZC / 4);
            const float4* ws4  = reinterpret_cast<const float4*>(sWsum);
            #pragma unroll
            for (int j4 = 0; j4 < DZC / 4; ++j4) {
                const float4 wq = WfcR[j4];
                const float4 s  = ws4[j4];
                u = fmaf(wq.x, s.x, u); u = fmaf(wq.y, s.y, u);
                u = fmaf(wq.z, s.z, u); u = fmaf(wq.w, s.w, u);
            }
        }
        sU[l] = u;
        float v1 = 0.0f, v2 = 0.0f;
        {
            const float4* W2R = reinterpret_cast<const float4*>(W2) + (size_t)l * (DPC / 4);
            const float4* su4 = reinterpret_cast<const float4*>(sU);
            const float4* sv4 = reinterpret_cast<const float4*>(sWv64);
            #pragma unroll
            for (int j4 = 0; j4 < DPC / 4; ++j4) {
                const float4 wq = W2R[j4];
                const float4 a  = su4[j4];
                const float4 b  = sv4[j4];
                v1 = fmaf(wq.x, a.x, v1); v1 = fmaf(wq.y, a.y, v1);
                v1 = fmaf(wq.z, a.z, v1); v1 = fmaf(wq.w, a.w, v1);
                v2 = fmaf(wq.x, b.x, v2); v2 = fmaf(wq.y, b.y, v2);
                v2 = fmaf(wq.z, b.z, v2); v2 = fmaf(wq.w, b.w, v2);
            }
        }
        float tb2u = b2v * u;
        float tb2w = b2v * wvv;
        #pragma unroll
        for (int m = 32; m >= 1; m >>= 1) {
            tb2u += __shfl_xor(tb2u, m);
            tb2w += __shfl_xor(tb2w, m);
        }
        sV1[l] = v1;
        sV2[l] = v2;
        if (l == 0) { sS[0] = tb2u; sS[1] = tb2w; }
    }

    // ---- pol/act shuffle trees, both envs (pre-barrier; R3/R8 order) ----
    float fqv[WENV], fpv[WENV];
    #pragma unroll
    for (int ee = 0; ee < WENV; ++ee) {
        float q0 = (pv0[ee] - av0[ee]) * va;
        float q1 = (pv1[ee] - av1[ee]) * va;
        float fq = q0 + q1;
        float fp = (pv0[ee] + pv1[ee]) * va;
        #pragma unroll
        for (int m = 1; m <= 4; m <<= 1) {
            q0 += __shfl_xor(q0, m);
            q1 += __shfl_xor(q1, m);
        }
        #pragma unroll
        for (int m = 32; m >= 1; m >>= 1) {
            fq += __shfl_xor(fq, m);
            fp += __shfl_xor(fp, m);
        }
        fqv[ee] = fq;
        fpv[ee] = fp;
        const int le = leA + ee;
        if ((l & 7) == 0) {
            sDv[le][l >> 3]       = q0;     // same-wave producer/consumer
            sDv[le][8 + (l >> 3)] = q1;
        }
    }

    __syncthreads();   // sW1T4 + sV1/sV2/sS visible (the ONLY barrier)

    // ---- issue env B obs loads NOW: their HBM latency hides under env A's
    //      compute below (deliberately post-barrier: __syncthreads may drain vmcnt). ----
    float4 ovB[8];
    #pragma unroll
    for (int t = 0; t < 8; ++t) ovB[t] = o4B[t * 64 + l];

    const float v1l  = sV1[l];
    const float v2l  = sV2[l];
    const float tb2u = sS[0];
    const float tb2w = sS[1];
    const float invN = 1.0f / 16.0f;
    const int   j0   = (4 * l) & 15;       // 0,4,8,12

    // ==== per-env pipeline stage (A then B) ====
    #pragma unroll
    for (int ee = 0; ee < WENV; ++ee) {
        const int le = leA + ee;
        float4* ov = (ee == 0) ? ovA : ovB;

        // obs mean, R1/R3 tree: zero-init + 8 adds, xor-32, *1/16.
        // lane l then holds agg[4c..4c+3], c = l&31 (duplicated across halves).
        float4 ag;
        {
            float4 a = make_float4(0.f, 0.f, 0.f, 0.f);
            #pragma unroll
            for (int t = 0; t < 8; ++t) {
                a.x += ov[t].x; a.y += ov[t].y; a.z += ov[t].z; a.w += ov[t].w;
            }
            a.x += __shfl_xor(a.x, 32);
            a.y += __shfl_xor(a.y, 32);
            a.z += __shfl_xor(a.z, 32);
            a.w += __shfl_xor(a.w, 32);
            ag = make_float4(a.x * invN, a.y * invN, a.z * invN, a.w * invN);
        }

        // mv1 (R8 chains: a0<-agg[4d4], a1<-agg[4d4+1], a2<-agg[4d4+2], a3<-agg[4d4+3])
        float a0 = b1v, a1 = 0.0f, a2 = 0.0f, a3 = 0.0f;
        #pragma unroll
        for (int d4 = 0; d4 < DIN / 4; ++d4) {
            const float4 w4 = sW1T4[l * 32 + (d4 ^ (l & 7))];
            a0 = fmaf(lane_bcast(ag.x, d4), w4.x, a0);
            a1 = fmaf(lane_bcast(ag.y, d4), w4.y, a1);
            a2 = fmaf(lane_bcast(ag.z, d4), w4.z, a2);
            a3 = fmaf(lane_bcast(ag.w, d4), w4.w, a3);
        }
        const float h = fmaxf((a0 + a1) + (a2 + a3), 0.0f);

        // scalars (R7/R8 trees)
        float t0 = h * v1l;
        float t1 = h * v2l;
        #pragma unroll
        for (int m = 32; m >= 1; m >>= 1) {
            t0 += __shfl_xor(t0, m);
            t1 += __shfl_xor(t1, m);
        }
        const float logit = t0 + tb2u;
        const float eV  = (logit > 0.0f) ? logit : 0.01f * logit;  // leaky slope 0.01
        const float wgt = 1.0f / (1.0f + expf(-eV));
        const float c   = t1 + tb2w + bvv;
        const float Sv  = fpv[ee] - wgt * fqv[ee];

        // outputs
        float4 xo, wo;
        xo.x = fmaf(wgt, sDv[le][j0 + 0], Sv) * invN + c;
        xo.y = fmaf(wgt, sDv[le][j0 + 1], Sv) * invN + c;
        xo.z = fmaf(wgt, sDv[le][j0 + 2], Sv) * invN + c;
        xo.w = fmaf(wgt, sDv[le][j0 + 3], Sv) * invN + c;
        wo.x = wo.y = wo.z = wo.w = wgt;

        const size_t base = (size_t)(blockIdx.x * GENV + le) * (NN * NN) + 4 * l;
        *reinterpret_cast<float4*>(out_x + base) = xo;
        *reinterpret_cast<float4*>(out_w + base) = wo;
    }
}

extern "C" void kernel_launch(void* const* d_in, const int* in_sizes, int n_in,
                              void* d_out, int out_size, void* d_ws, size_t ws_size,
                              hipStream_t stream) {
    const float* obs      = (const float*)d_in[0];
    const float* policies = (const float*)d_in[1];
    const float* actions  = (const float*)d_in[2];
    const float* W1       = (const float*)d_in[3];
    const float* b1       = (const float*)d_in[4];
    const float* W2       = (const float*)d_in[5];
    const float* b2       = (const float*)d_in[6];
    const float* Wfc      = (const float*)d_in[7];
    const float* Wattn    = (const float*)d_in[8];
    const float* Wv       = (const float*)d_in[9];
    const float* bv       = (const float*)d_in[10];

    float* out_x = (float*)d_out;                    // [B*N*N] = 1048576
    float* out_w = out_x + (size_t)BB * NN * NN;     // second tuple element

    critic_kernel<<<BB / GENV, NTHR, 0, stream>>>(obs, policies, actions,
                                                  W1, b1, W2, b2, Wfc, Wattn, Wv, bv,
                                                  out_x, out_w);
}